// Round 5
// baseline (818.351 us; speedup 1.0000x reference)
//
#include <hip/hip_runtime.h>
#include <hip/hip_bf16.h>
#include <cstdint>
#include <cstddef>

// BimodalAttention on MI355X.
// Algebra: seq_rep = softmax_t(f@cv) . f,  f = tanh(X@M + bias_eff),
//   X = [S1|S2] (32768x2048), M = [W1@Wtop ; W2@Wbot] (2048x1024),
//   bias_eff = b1@Wtop + b2@Wbot + Wb.
// Precision: fp32 emulated via bf16 split (hi+lo), 3 MFMAs per tile pair.

typedef __attribute__((ext_vector_type(8))) short short8;
typedef __attribute__((ext_vector_type(4))) float f32x4;
typedef __attribute__((ext_vector_type(4))) unsigned short u16x4;

#define DEVINL static __device__ __forceinline__

DEVINL unsigned short bf16_rne(float f) {
  uint32_t u = __float_as_uint(f);
  uint32_t r = (u + 0x7FFFu + ((u >> 16) & 1u)) >> 16;
  return (unsigned short)r;
}
DEVINL float bf16f(unsigned short h) { return __uint_as_float(((uint32_t)h) << 16); }

// 16B-chunk XOR swizzle: logical (row r, k-chunk q in [0,4)) -> physical chunk.
// 2-way (free) bank aliasing on fragment ds_read_b128.
DEVINL int lds_chunk(int r, int q) { return (r << 2) + (q ^ ((r >> 1) & 3)); }

DEVINL void gload_lds16(const void* g, void* l) {
  __builtin_amdgcn_global_load_lds(
      (const __attribute__((address_space(1))) uint32_t*)g,
      (__attribute__((address_space(3))) uint32_t*)l, 16, 0, 0);
}

DEVINL float fast_tanh(float x) {
  float e = __expf(2.0f * x);
  return 1.0f - 2.0f / (e + 1.0f);
}

// ---------------------------------------------------------------------------
// GEMM with bf16x3 emulated-fp32 MFMA.
// MODE 0: prep  — C = A(z) @ B,  A = W1/W2 fp32 (split in-kernel),
//         B = Wt (pre-split, transposed), K=1024; writes Mt hi/lo transposed.
// MODE 1/2: main — C = X @ M, A = [S1|S2] fp32, B = Mt hi/lo, K=2048;
//         epilogue: bias + tanh + feature store (1: f32, 2: bf16) + scores.
// ---------------------------------------------------------------------------
template<int MFR, int NFR, int WMW, int WNW, int MODE>
__global__ __launch_bounds__(WMW*WNW*64, 2)
void gemm3x(const float* __restrict__ A1, const float* __restrict__ A2,
            const unsigned short* __restrict__ Bh, const unsigned short* __restrict__ Bl,
            unsigned short* __restrict__ Mh, unsigned short* __restrict__ Ml,
            const float* __restrict__ bias_eff, const float* __restrict__ cvec,
            void* __restrict__ feat, float* __restrict__ scores)
{
  constexpr int WTM = MFR * 16, WTN = NFR * 16;
  constexpr int BM = WMW * WTM, BN = WNW * WTN;
  constexpr int NT = WMW * WNW * 64;
  constexpr int NWAVES = NT / 64;
  constexpr int AHI = 0, ALO = BM * 32, BHI = 2 * BM * 32, BLO = 2 * BM * 32 + BN * 32;
  constexpr int BUFSZ = 2 * BM * 32 + 2 * BN * 32;  // ushorts per buffer
  constexpr int AITER = (BM * 4) / NT;              // A chunk-stages per thread
  constexpr int KSTEPS = (MODE == 0) ? 32 : 64;     // K/32
  static_assert((BM * 4) % NT == 0, "A staging mapping");
  static_assert((BN * 4) % (64 * NWAVES) == 0, "B staging mapping");

  __shared__ __attribute__((aligned(16))) unsigned short sm[2 * BUFSZ];

  const int tid = threadIdx.x;
  const int lane = tid & 63;
  const int wid = tid >> 6;
  const int wm = wid / WNW, wn = wid % WNW;

  int bm, bn, zsel, bkoff;
  if constexpr (MODE == 0) {
    bm = blockIdx.x; bn = blockIdx.y; zsel = blockIdx.z; bkoff = zsel * 1024;
  } else {
    // Bijective XCD-chunked swizzle: xcd = g&7 owns 32 consecutive row-bands;
    // col-band fastest within XCD so A panels stay hot in that XCD's L2.
    int g = blockIdx.x;
    int xcd = g & 7, idx = g >> 3;        // idx in [0, 256)
    bn = idx & 7;                          // 8 col-bands (N=1024 / 128)
    bm = (xcd << 5) | (idx >> 3);          // 256 row-bands (M=32768 / 128)
    zsel = 0; bkoff = 0;
  }
  const float* Asel = (MODE == 0) ? (zsel ? A2 : A1) : nullptr;

  f32x4 acc[MFR][NFR];
  #pragma unroll
  for (int i = 0; i < MFR; ++i)
    #pragma unroll
    for (int j = 0; j < NFR; ++j) acc[i][j] = (f32x4){0.f, 0.f, 0.f, 0.f};

  float areg[AITER][8];

  auto stageB = [&](int bsel, int k0) {
    #pragma unroll
    for (int c = 0; c < (BN * 4) / 64 / NWAVES; ++c) {
      int call = wid + c * NWAVES;
      int chunk = call * 64 + lane;
      int r = chunk >> 2, qs = chunk & 3;
      int ql = qs ^ ((r >> 1) & 3);  // pre-swizzled source; linear LDS dest
      size_t gidx = (size_t)(bn * BN + r) * 2048 + (size_t)(bkoff + k0 + ql * 8);
      gload_lds16(Bh + gidx, (void*)&sm[bsel * BUFSZ + BHI + call * 512]);
      gload_lds16(Bl + gidx, (void*)&sm[bsel * BUFSZ + BLO + call * 512]);
    }
  };

  auto stageA_load = [&](int k0) {
    #pragma unroll
    for (int it = 0; it < AITER; ++it) {
      int e = tid + it * NT;
      int r = e >> 2, q = e & 3;
      size_t row = (size_t)(bm * BM + r);
      const float* src;
      if constexpr (MODE == 0) {
        src = Asel + row * 1024 + (k0 + q * 8);
      } else {
        const float* base = (k0 < 1024) ? A1 : A2;
        src = base + row * 1024 + ((k0 & 1023) + q * 8);
      }
      float4 v0 = *(const float4*)(src);
      float4 v1 = *(const float4*)(src + 4);
      areg[it][0] = v0.x; areg[it][1] = v0.y; areg[it][2] = v0.z; areg[it][3] = v0.w;
      areg[it][4] = v1.x; areg[it][5] = v1.y; areg[it][6] = v1.z; areg[it][7] = v1.w;
    }
  };

  auto stageA_write = [&](int bsel) {
    #pragma unroll
    for (int it = 0; it < AITER; ++it) {
      int e = tid + it * NT;
      int r = e >> 2, q = e & 3;
      short8 hi, lo;
      #pragma unroll
      for (int j = 0; j < 8; ++j) {
        float x = areg[it][j];
        unsigned short h = bf16_rne(x);
        hi[j] = (short)h;
        lo[j] = (short)bf16_rne(x - bf16f(h));
      }
      int ch = lds_chunk(r, q);
      *(short8*)(&sm[bsel * BUFSZ + AHI + ch * 8]) = hi;
      *(short8*)(&sm[bsel * BUFSZ + ALO + ch * 8]) = lo;
    }
  };

  auto compute = [&](int bsel) {
    short8 bh[NFR], bl[NFR];
    #pragma unroll
    for (int nf = 0; nf < NFR; ++nf) {
      int nl = wn * WTN + nf * 16 + (lane & 15);
      int ch = lds_chunk(nl, lane >> 4);
      bh[nf] = *(const short8*)(&sm[bsel * BUFSZ + BHI + ch * 8]);
      bl[nf] = *(const short8*)(&sm[bsel * BUFSZ + BLO + ch * 8]);
    }
    #pragma unroll
    for (int mf = 0; mf < MFR; ++mf) {
      int ml = wm * WTM + mf * 16 + (lane & 15);
      int ch = lds_chunk(ml, lane >> 4);
      short8 ah = *(const short8*)(&sm[bsel * BUFSZ + AHI + ch * 8]);
      short8 al = *(const short8*)(&sm[bsel * BUFSZ + ALO + ch * 8]);
      #pragma unroll
      for (int nf = 0; nf < NFR; ++nf) {
        acc[mf][nf] = __builtin_amdgcn_mfma_f32_16x16x32_bf16(ah, bh[nf], acc[mf][nf], 0, 0, 0);
        acc[mf][nf] = __builtin_amdgcn_mfma_f32_16x16x32_bf16(al, bh[nf], acc[mf][nf], 0, 0, 0);
        acc[mf][nf] = __builtin_amdgcn_mfma_f32_16x16x32_bf16(ah, bl[nf], acc[mf][nf], 0, 0, 0);
      }
    }
  };

  // prologue
  stageB(0, 0);
  stageA_load(0);
  stageA_write(0);
  __syncthreads();

  for (int t = 0; t < KSTEPS; ++t) {
    int cur = t & 1;
    if (t + 1 < KSTEPS) { stageB(cur ^ 1, (t + 1) * 32); stageA_load((t + 1) * 32); }
    compute(cur);
    if (t + 1 < KSTEPS) stageA_write(cur ^ 1);
    __syncthreads();  // drains vmcnt (gload_lds) + lgkm (ds_write)
  }

  if constexpr (MODE == 0) {
    const int zoff = zsel * 1024;
    #pragma unroll
    for (int nf = 0; nf < NFR; ++nf) {
      int u = bn * BN + wn * WTN + nf * 16 + (lane & 15);
      #pragma unroll
      for (int mf = 0; mf < MFR; ++mf) {
        int d0 = bm * BM + wm * WTM + mf * 16 + ((lane >> 4) << 2);
        u16x4 h4, l4;
        #pragma unroll
        for (int i = 0; i < 4; ++i) {
          float v = acc[mf][nf][i];
          unsigned short h = bf16_rne(v);
          h4[i] = h;
          l4[i] = bf16_rne(v - bf16f(h));
        }
        *(u16x4*)(Mh + (size_t)u * 2048 + zoff + d0) = h4;
        *(u16x4*)(Ml + (size_t)u * 2048 + zoff + d0) = l4;
      }
    }
  } else {
    float bia[NFR], cvv[NFR];
    int ncol[NFR];
    #pragma unroll
    for (int nf = 0; nf < NFR; ++nf) {
      ncol[nf] = bn * BN + wn * WTN + nf * 16 + (lane & 15);
      bia[nf] = bias_eff[ncol[nf]];
      cvv[nf] = cvec[ncol[nf]];
    }
    #pragma unroll
    for (int mf = 0; mf < MFR; ++mf) {
      int r0 = bm * BM + wm * WTM + mf * 16 + ((lane >> 4) << 2);
      float sp[4] = {0.f, 0.f, 0.f, 0.f};
      #pragma unroll
      for (int nf = 0; nf < NFR; ++nf) {
        #pragma unroll
        for (int i = 0; i < 4; ++i) {
          float f = fast_tanh(acc[mf][nf][i] + bia[nf]);
          size_t idx = (size_t)(r0 + i) * 1024 + ncol[nf];
          if constexpr (MODE == 1) ((float*)feat)[idx] = f;
          else                     ((unsigned short*)feat)[idx] = bf16_rne(f);
          sp[i] += f * cvv[nf];
        }
      }
      #pragma unroll
      for (int i = 0; i < 4; ++i) {
        float s = sp[i];
        s += __shfl_xor(s, 1); s += __shfl_xor(s, 2);
        s += __shfl_xor(s, 4); s += __shfl_xor(s, 8);
        if ((lane & 15) == 0) atomicAdd(&scores[r0 + i], s);
      }
    }
  }
}

// ---------------------------------------------------------------------------
// W (2048x1024 f32) -> Wt hi/lo (1024x2048 bf16, transposed + split)
// ---------------------------------------------------------------------------
__global__ __launch_bounds__(256)
void split_transpose_w(const float* __restrict__ W,
                       unsigned short* __restrict__ Wt_h,
                       unsigned short* __restrict__ Wt_l)
{
  __shared__ float tsm[64][68];
  const int j0 = blockIdx.x * 64, u0 = blockIdx.y * 64;
  const int tid = threadIdx.x;
  const int jr = tid >> 4, uc = (tid & 15) * 4;
  #pragma unroll
  for (int rr = 0; rr < 4; ++rr) {
    int j = jr + rr * 16;
    float4 v = *(const float4*)(W + (size_t)(j0 + j) * 1024 + u0 + uc);
    tsm[j][uc + 0] = v.x; tsm[j][uc + 1] = v.y;
    tsm[j][uc + 2] = v.z; tsm[j][uc + 3] = v.w;
  }
  __syncthreads();
  const int ul = tid & 63, seg = tid >> 6;
  short8 h8[2], l8[2];
  #pragma unroll
  for (int k = 0; k < 16; ++k) {
    float v = tsm[seg * 16 + k][ul];
    unsigned short h = bf16_rne(v);
    h8[k >> 3][k & 7] = (short)h;
    l8[k >> 3][k & 7] = (short)bf16_rne(v - bf16f(h));
  }
  size_t ob = (size_t)(u0 + ul) * 2048 + j0 + seg * 16;
  *(short8*)(Wt_h + ob) = h8[0];
  *(short8*)(Wt_h + ob + 8) = h8[1];
  *(short8*)(Wt_l + ob) = l8[0];
  *(short8*)(Wt_l + ob + 8) = l8[1];
}

__global__ __launch_bounds__(256)
void bias_eff_k(const float* __restrict__ b1, const float* __restrict__ b2,
                const float* __restrict__ W, const float* __restrict__ Wb,
                float* __restrict__ bias_eff)
{
  int u = blockIdx.x * 256 + threadIdx.x;
  float acc = Wb[u];
  for (int j = 0; j < 1024; ++j) {
    acc = fmaf(b1[j], W[(size_t)j * 1024 + u], acc);
    acc = fmaf(b2[j], W[(size_t)(j + 1024) * 1024 + u], acc);
  }
  bias_eff[u] = acc;
}

// softmax over T=2048 per batch
__global__ __launch_bounds__(256)
void softmax_t(const float* __restrict__ scores, float* __restrict__ weights)
{
  __shared__ float rmax[4], rsum[4];
  const int b = blockIdx.x, tid = threadIdx.x;
  const int lane = tid & 63, wid = tid >> 6;
  float v[8];
  float mx = -3.0e38f;
  #pragma unroll
  for (int i = 0; i < 8; ++i) {
    v[i] = scores[b * 2048 + i * 256 + tid];
    mx = fmaxf(mx, v[i]);
  }
  #pragma unroll
  for (int m = 1; m < 64; m <<= 1) mx = fmaxf(mx, __shfl_xor(mx, m));
  if (lane == 0) rmax[wid] = mx;
  __syncthreads();
  mx = fmaxf(fmaxf(rmax[0], rmax[1]), fmaxf(rmax[2], rmax[3]));
  float s = 0.f;
  #pragma unroll
  for (int i = 0; i < 8; ++i) { v[i] = __expf(v[i] - mx); s += v[i]; }
  #pragma unroll
  for (int m = 1; m < 64; m <<= 1) s += __shfl_xor(s, m);
  if (lane == 0) rsum[wid] = s;
  __syncthreads();
  s = rsum[0] + rsum[1] + rsum[2] + rsum[3];
  float inv = 1.0f / s;
  #pragma unroll
  for (int i = 0; i < 8; ++i) weights[b * 2048 + i * 256 + tid] = v[i] * inv;
}

// seq_rep[b,u] = sum_t w[b,t] * f[b,t,u]; T split into 16 chunks of 128
// for full-chip HBM streaming (256 blocks).
template<int F32>
__global__ __launch_bounds__(256)
void weighted_sum_k(const float* __restrict__ weights, const void* __restrict__ feat,
                    float* __restrict__ out)
{
  const int b = blockIdx.x >> 4, tc = blockIdx.x & 15;
  const int tid = threadIdx.x;
  float a0 = 0.f, a1 = 0.f, a2 = 0.f, a3 = 0.f;
  const int t0 = tc * 128;
  for (int t = 0; t < 128; ++t) {
    int row = b * 2048 + t0 + t;
    float wgt = weights[row];
    if constexpr (F32) {
      float4 f = *((const float4*)feat + (size_t)row * 256 + tid);
      a0 = fmaf(wgt, f.x, a0); a1 = fmaf(wgt, f.y, a1);
      a2 = fmaf(wgt, f.z, a2); a3 = fmaf(wgt, f.w, a3);
    } else {
      u16x4 f = *((const u16x4*)feat + (size_t)row * 256 + tid);
      a0 = fmaf(wgt, bf16f(f[0]), a0); a1 = fmaf(wgt, bf16f(f[1]), a1);
      a2 = fmaf(wgt, bf16f(f[2]), a2); a3 = fmaf(wgt, bf16f(f[3]), a3);
    }
  }
  float* o = out + b * 1024 + tid * 4;
  atomicAdd(o + 0, a0); atomicAdd(o + 1, a1);
  atomicAdd(o + 2, a2); atomicAdd(o + 3, a3);
}

extern "C" void kernel_launch(void* const* d_in, const int* in_sizes, int n_in,
                              void* d_out, int out_size, void* d_ws, size_t ws_size,
                              hipStream_t stream)
{
  (void)in_sizes; (void)n_in;
  const float* S1 = (const float*)d_in[0];
  const float* S2 = (const float*)d_in[1];
  const float* W1 = (const float*)d_in[2];
  const float* b1 = (const float*)d_in[3];
  const float* W2 = (const float*)d_in[4];
  const float* b2 = (const float*)d_in[5];
  const float* Wk = (const float*)d_in[6];
  const float* Wb = (const float*)d_in[7];
  const float* cv = (const float*)d_in[8];

  char* p = (char*)d_ws;
  unsigned short* Mt_h = (unsigned short*)p; p += (size_t)1024 * 2048 * 2;
  unsigned short* Mt_l = (unsigned short*)p; p += (size_t)1024 * 2048 * 2;
  unsigned short* Wt_h = (unsigned short*)p; p += (size_t)1024 * 2048 * 2;
  unsigned short* Wt_l = (unsigned short*)p; p += (size_t)1024 * 2048 * 2;
  float* bias_eff = (float*)p; p += 4096;
  float* scores   = (float*)p; p += (size_t)32768 * 4;
  float* weights  = (float*)p; p += (size_t)32768 * 4;
  void* feat = (void*)p;
  size_t base = (size_t)(p - (char*)d_ws);
  // fp32 features if workspace allows (numeric safety), else bf16.
  bool f32feat = (ws_size >= base + (size_t)32768 * 1024 * 4);

  hipMemsetAsync(scores, 0, 32768 * 4, stream);
  hipMemsetAsync(d_out, 0, (size_t)out_size * 4, stream);

  split_transpose_w<<<dim3(32, 16, 1), 256, 0, stream>>>(Wk, Wt_h, Wt_l);
  bias_eff_k<<<dim3(4, 1, 1), 256, 0, stream>>>(b1, b2, Wk, Wb, bias_eff);

  // prep: M = [W1@Wtop ; W2@Wbot], written transposed + split.
  // BN=64 -> grid 8x16x2 = 256 blocks (full-chip; was 128).
  gemm3x<4, 2, 2, 2, 0><<<dim3(8, 16, 2), 256, 0, stream>>>(
      W1, W2, Wt_h, Wt_l, Mt_h, Mt_l, nullptr, nullptr, nullptr, nullptr);

  // main: f = tanh(X@M + bias_eff), fused scores partials.
  // 128x128 tile / 4 waves / 64 KiB LDS -> 2 blocks/CU (m103: 128^2 beats
  // 256^2 for the 2-barrier structure; avoids the m132 occupancy cliff).
  if (f32feat)
    gemm3x<4, 4, 2, 2, 1><<<dim3(2048, 1, 1), 256, 0, stream>>>(
        S1, S2, Mt_h, Mt_l, nullptr, nullptr, bias_eff, cv, feat, scores);
  else
    gemm3x<4, 4, 2, 2, 2><<<dim3(2048, 1, 1), 256, 0, stream>>>(
        S1, S2, Mt_h, Mt_l, nullptr, nullptr, bias_eff, cv, feat, scores);

  softmax_t<<<dim3(16, 1, 1), 256, 0, stream>>>(scores, weights);

  if (f32feat)
    weighted_sum_k<1><<<dim3(256, 1, 1), 256, 0, stream>>>(weights, feat, (float*)d_out);
  else
    weighted_sum_k<0><<<dim3(256, 1, 1), 256, 0, stream>>>(weights, feat, (float*)d_out);
}